// Round 1
// baseline (115.077 us; speedup 1.0000x reference)
//
#include <hip/hip_runtime.h>
#include <hip/hip_bf16.h>

#define BB 2
#define NN 384
#define DIM 256
#define HID 128
#define ROWS (BB*NN)   // 768

typedef __attribute__((ext_vector_type(8))) short bf16x8;
typedef __attribute__((ext_vector_type(4))) float f32x4;

static __device__ __forceinline__ unsigned int f2bf(float f) {
    unsigned int u = __builtin_bit_cast(unsigned int, f);
    return (u + 0x7FFFu + ((u >> 16) & 1u)) >> 16;   // RNE bf16 bits in low 16
}

// ---------------- qkv = x @ qkv_w + qkv_b  (f32) ----------------
__global__ __launch_bounds__(256) void qkv_gemm(const float* __restrict__ x,
        const float* __restrict__ w, const float* __restrict__ bias,
        float* __restrict__ out) {
    __shared__ float xs[4][DIM];
    const int r0 = blockIdx.x * 4;
    const int t = threadIdx.x;
    #pragma unroll
    for (int i = 0; i < 4; ++i) xs[i][t] = x[(r0 + i) * DIM + t];
    __syncthreads();
    float acc[4][3];
    #pragma unroll
    for (int r = 0; r < 4; ++r) { acc[r][0]=0.f; acc[r][1]=0.f; acc[r][2]=0.f; }
    for (int k = 0; k < DIM; k += 4) {
        float4 xv[4];
        #pragma unroll
        for (int r = 0; r < 4; ++r) xv[r] = *(const float4*)&xs[r][k];
        #pragma unroll
        for (int kk = 0; kk < 4; ++kk) {
            float w0 = w[(k+kk)*768 + t];
            float w1v = w[(k+kk)*768 + t + 256];
            float w2v = w[(k+kk)*768 + t + 512];
            #pragma unroll
            for (int r = 0; r < 4; ++r) {
                float xr = kk==0?xv[r].x : kk==1?xv[r].y : kk==2?xv[r].z : xv[r].w;
                acc[r][0] += xr*w0; acc[r][1] += xr*w1v; acc[r][2] += xr*w2v;
            }
        }
    }
    #pragma unroll
    for (int r = 0; r < 4; ++r) {
        out[(r0+r)*768 + t]       = acc[r][0] + bias[t];
        out[(r0+r)*768 + t + 256] = acc[r][1] + bias[t+256];
        out[(r0+r)*768 + t + 512] = acc[r][2] + bias[t+512];
    }
}

// ---------------- w2 [128][256] f32 -> w2t [256][128] bf16 ----------------
__global__ __launch_bounds__(256) void w2_prep(const float* __restrict__ w2,
        unsigned short* __restrict__ w2t) {
    int g = blockIdx.x * 256 + threadIdx.x;   // g = h*256 + c
    int h = g >> 8, c = g & 255;
    w2t[c * HID + h] = (unsigned short)f2bf(w2[g]);
}

// ---------------- fused rel-pos MLP + per-channel online softmax ----------------
__global__ __launch_bounds__(256, 2) void attn_main(
        const float* __restrict__ qkv,          // [ROWS][768] (q|k|v)
        const float* __restrict__ pos,          // [ROWS][3]
        const unsigned char* __restrict__ mask, // [ROWS] (bool)
        const float* __restrict__ w1,           // [HID]
        const float* __restrict__ b1,           // [HID]
        const unsigned short* __restrict__ w2t, // [256][128] bf16, c-major
        const float* __restrict__ b2,           // [DIM]
        float* __restrict__ out_pre)            // [ROWS][DIM]
{
    __shared__ unsigned short w2l[DIM][HID];  // swizzled 16B units: u' = u ^ ((c&3)<<2)
    __shared__ unsigned short hl[32][HID];    // swizzled:           u' = u ^ ((j&3)<<2)
    __shared__ float w1s[HID], b1s[HID];

    const int tid = threadIdx.x;
    const int row = blockIdx.x;               // b*N + i
    const int b = row / NN;
    const int l = tid & 63;
    const int wv = tid >> 6;
    const int cbase = wv * 64;

    // stage w2 bf16 into LDS with swizzle (coalesced 16B chunks)
    #pragma unroll
    for (int it = 0; it < 16; ++it) {
        int f = tid + (it << 8);              // chunk id: c = f>>4, u = f&15
        int c = f >> 4, u = f & 15;
        int up = u ^ ((c & 3) << 2);
        *(uint4*)&w2l[c][up * 8] = *(const uint4*)(w2t + c * HID + u * 8);
    }
    if (tid < HID) { w1s[tid] = w1[tid]; b1s[tid] = b1[tid]; }
    __syncthreads();

    // cache all B fragments (w2) in registers: 16 frags x 16B
    bf16x8 Bc[4][4];
    #pragma unroll
    for (int ct = 0; ct < 4; ++ct)
        #pragma unroll
        for (int kk = 0; kk < 4; ++kk) {
            int c = cbase + ct * 16 + (l & 15);
            int u = kk * 4 + (l >> 4);
            int up = u ^ ((c & 3) << 2);
            Bc[ct][kk] = *(const bf16x8*)&w2l[c][up * 8];
        }

    float kqv[4], b2v[4];
    #pragma unroll
    for (int ct = 0; ct < 4; ++ct) {
        int c = cbase + ct * 16 + (l & 15);
        kqv[ct] = qkv[row * 768 + 256 + c];   // x_k[b,i,c]
        b2v[ct] = b2[c];
    }
    const float pix = pos[row*3+0], piy = pos[row*3+1], piz = pos[row*3+2];
    const bool mi = mask[row] != 0;

    float m[4], s[4], o[4];
    #pragma unroll
    for (int ct = 0; ct < 4; ++ct) { m[ct] = -INFINITY; s[ct] = 0.f; o[ct] = 0.f; }

    for (int jb = 0; jb < NN; jb += 32) {
        __syncthreads();   // hl consumed by previous iteration
        // stage h tile: h[j][k] = relu(d_ij * w1[k] + b1[k]) as bf16
        #pragma unroll
        for (int it = 0; it < 2; ++it) {
            int item = tid + (it << 8);       // 0..511
            int jl = item >> 4;               // 0..31
            int u  = item & 15;               // k-group of 8
            int j  = jb + jl;
            float dx = pix - pos[(b*NN + j)*3 + 0];
            float dy = piy - pos[(b*NN + j)*3 + 1];
            float dz = piz - pos[(b*NN + j)*3 + 2];
            float sq = dx*dx + dy*dy + dz*dz;
            float d  = sq > 0.f ? sqrtf(sq) : 0.f;
            float4 wa = *(const float4*)&w1s[u*8];
            float4 wb = *(const float4*)&w1s[u*8+4];
            float4 ba = *(const float4*)&b1s[u*8];
            float4 bb = *(const float4*)&b1s[u*8+4];
            float h0 = fmaxf(d*wa.x + ba.x, 0.f), h1 = fmaxf(d*wa.y + ba.y, 0.f);
            float h2 = fmaxf(d*wa.z + ba.z, 0.f), h3 = fmaxf(d*wa.w + ba.w, 0.f);
            float h4 = fmaxf(d*wb.x + bb.x, 0.f), h5 = fmaxf(d*wb.y + bb.y, 0.f);
            float h6 = fmaxf(d*wb.z + bb.z, 0.f), h7 = fmaxf(d*wb.w + bb.w, 0.f);
            uint4 pkt;
            pkt.x = f2bf(h0) | (f2bf(h1) << 16);
            pkt.y = f2bf(h2) | (f2bf(h3) << 16);
            pkt.z = f2bf(h4) | (f2bf(h5) << 16);
            pkt.w = f2bf(h6) | (f2bf(h7) << 16);
            int up = u ^ ((jl & 3) << 2);
            *(uint4*)&hl[jl][up * 8] = pkt;
        }
        __syncthreads();

        #pragma unroll
        for (int jt = 0; jt < 2; ++jt) {
            bf16x8 Af[4];
            #pragma unroll
            for (int kk = 0; kk < 4; ++kk) {
                int jl = jt * 16 + (l & 15);
                int u  = kk * 4 + (l >> 4);
                int up = u ^ ((jl & 3) << 2);
                Af[kk] = *(const bf16x8*)&hl[jl][up * 8];
            }
            #pragma unroll
            for (int ct = 0; ct < 4; ++ct) {
                f32x4 acc = {0.f, 0.f, 0.f, 0.f};
                #pragma unroll
                for (int kk = 0; kk < 4; ++kk)
                    acc = __builtin_amdgcn_mfma_f32_16x16x32_bf16(Af[kk], Bc[ct][kk], acc, 0, 0, 0);

                int c = cbase + ct * 16 + (l & 15);
                int jrow0 = jb + jt * 16 + ((l >> 4) << 2);
                float logit[4], vval[4];
                #pragma unroll
                for (int r = 0; r < 4; ++r) {
                    int j = jrow0 + r;
                    float rp = acc[r] + b2v[ct];                 // SCALE = 1
                    float qv = qkv[(b*NN + j)*768 + c];          // x_q[b,j,c]
                    float vv = qkv[(b*NN + j)*768 + 512 + c];    // x_v[b,j,c]
                    logit[r] = kqv[ct] * qv + rp;
                    vval[r]  = vv + rp;
                }
                if (mi) {   // pair mask = mask_i & mask_j (all-false in practice)
                    #pragma unroll
                    for (int r = 0; r < 4; ++r)
                        if (mask[b*NN + jrow0 + r]) logit[r] = -INFINITY;
                }
                float tmax = fmaxf(fmaxf(logit[0], logit[1]), fmaxf(logit[2], logit[3]));
                tmax = fmaxf(tmax, __shfl_xor(tmax, 16, 64));
                tmax = fmaxf(tmax, __shfl_xor(tmax, 32, 64));
                float newm = fmaxf(m[ct], tmax);
                float sc = __expf(m[ct] - newm);
                s[ct] *= sc; o[ct] *= sc; m[ct] = newm;
                #pragma unroll
                for (int r = 0; r < 4; ++r) {
                    float p = __expf(logit[r] - newm);
                    s[ct] += p;
                    o[ct] += p * vval[r];
                }
            }
        }
    }

    // reduce partial (s,o) across the 4 row-groups; write 64 channels per wave
    #pragma unroll
    for (int ct = 0; ct < 4; ++ct) {
        float sv = s[ct], ov = o[ct];
        sv += __shfl_xor(sv, 16, 64); ov += __shfl_xor(ov, 16, 64);
        sv += __shfl_xor(sv, 32, 64); ov += __shfl_xor(ov, 32, 64);
        if (l < 16) out_pre[row * DIM + cbase + ct * 16 + l] = ov / sv;
    }
}

// ---------------- out = out_pre @ out_w + out_b (f32) ----------------
__global__ __launch_bounds__(256) void out_gemm(const float* __restrict__ a,
        const float* __restrict__ w, const float* __restrict__ bias,
        float* __restrict__ out) {
    __shared__ float as[4][DIM];
    const int r0 = blockIdx.x * 4;
    const int t = threadIdx.x;
    #pragma unroll
    for (int i = 0; i < 4; ++i) as[i][t] = a[(r0 + i) * DIM + t];
    __syncthreads();
    float acc[4] = {0.f, 0.f, 0.f, 0.f};
    for (int k = 0; k < DIM; k += 4) {
        float4 xv[4];
        #pragma unroll
        for (int r = 0; r < 4; ++r) xv[r] = *(const float4*)&as[r][k];
        #pragma unroll
        for (int kk = 0; kk < 4; ++kk) {
            float wv = w[(k+kk)*DIM + t];
            #pragma unroll
            for (int r = 0; r < 4; ++r) {
                float xr = kk==0?xv[r].x : kk==1?xv[r].y : kk==2?xv[r].z : xv[r].w;
                acc[r] += xr * wv;
            }
        }
    }
    #pragma unroll
    for (int r = 0; r < 4; ++r) out[(r0+r)*DIM + t] = acc[r] + bias[t];
}

extern "C" void kernel_launch(void* const* d_in, const int* in_sizes, int n_in,
                              void* d_out, int out_size, void* d_ws, size_t ws_size,
                              hipStream_t stream) {
    const float* x      = (const float*)d_in[0];
    const float* pos    = (const float*)d_in[1];
    const unsigned char* mask = (const unsigned char*)d_in[2];
    const float* qkv_w  = (const float*)d_in[3];
    const float* qkv_b  = (const float*)d_in[4];
    const float* pm_w1  = (const float*)d_in[5];
    const float* pm_b1  = (const float*)d_in[6];
    const float* pm_w2  = (const float*)d_in[7];
    const float* pm_b2  = (const float*)d_in[8];
    const float* out_w  = (const float*)d_in[9];
    const float* out_b  = (const float*)d_in[10];
    float* out = (float*)d_out;

    char* ws = (char*)d_ws;
    float* qkv            = (float*)ws;                         // 768*768*4 = 2,359,296 B
    float* out_pre        = (float*)(ws + 2359296);             //   786,432 B
    unsigned short* w2t   = (unsigned short*)(ws + 2359296 + 786432); // 65,536 B

    hipLaunchKernelGGL(qkv_gemm, dim3(ROWS/4), dim3(256), 0, stream, x, qkv_w, qkv_b, qkv);
    hipLaunchKernelGGL(w2_prep,  dim3(HID*DIM/256), dim3(256), 0, stream, pm_w2, w2t);
    hipLaunchKernelGGL(attn_main, dim3(ROWS), dim3(256), 0, stream,
                       qkv, pos, mask, pm_w1, pm_b1, w2t, pm_b2, out_pre);
    hipLaunchKernelGGL(out_gemm, dim3(ROWS/4), dim3(256), 0, stream, out_pre, out_w, out_b, out);
}